// Round 5
// baseline (835.709 us; speedup 1.0000x reference)
//
#include <hip/hip_runtime.h>

// Problem constants (fixed by setup_inputs): B=512, S=512, D=512
#define NB 512
#define NS 512
#define ND 512
#define INV_SCALE 0.125f   // 1/sqrt(D/8=64)
#define LN_EPS 1e-5f

typedef __attribute__((ext_vector_type(8))) short short8;
typedef __attribute__((ext_vector_type(4))) short short4v;
typedef __attribute__((ext_vector_type(4))) float float4v;

static __device__ __forceinline__ unsigned short f2bf(float x) {
    unsigned int u = __float_as_uint(x);
    unsigned int r = (u + 0x7fffu + ((u >> 16) & 1u)) >> 16;
    return (unsigned short)r;
}
static __device__ __forceinline__ float bf2f(unsigned short h) {
    return __uint_as_float(((unsigned int)h) << 16);
}

// 64-lane dot of row x[0..511] with hoisted weight halves w0,w1
static __device__ __forceinline__ float dot512(const float* __restrict__ x,
                                               float4 w0, float4 w1, int lane) {
    float4 a0 = *(const float4*)(x + 4 * lane);
    float4 a1 = *(const float4*)(x + 256 + 4 * lane);
    float d = a0.x * w0.x + a0.y * w0.y + a0.z * w0.z + a0.w * w0.w +
              a1.x * w1.x + a1.y * w1.y + a1.z * w1.z + a1.w * w1.w;
    for (int off = 32; off; off >>= 1) d += __shfl_xor(d, off, 64);
    return d;
}

// ---------------------------------------------------------------------------
// prep_k (280 blocks x 256): weight-only precomputation.
//   0..255   Wqk = Wq @ Wk^T (32x32 split-bf16 MFMA tiles; R2-proven code)
//   256..263 wv[m]  = Wq[m,:]·bk          (64 rows/block)
//   264..271 bqk[n] = bq·Wk[n,:]  (+c0=bq·bk in block 264)
//   272..279 bvo[n] = (bv@Wo)[n] + bo[n]  (64 cols/block)
// ---------------------------------------------------------------------------
__global__ __launch_bounds__(256) void prep_k(
    const float* __restrict__ Wq, const float* __restrict__ Wk,
    const float* __restrict__ bq, const float* __restrict__ bk,
    const float* __restrict__ bv, const float* __restrict__ Wo,
    const float* __restrict__ bo,
    float* __restrict__ Wqk, float* __restrict__ wv,
    float* __restrict__ bqk, float* __restrict__ bvo, float* __restrict__ c0) {
    const int bid = blockIdx.x;
    const int t = threadIdx.x;
    const int wave = t >> 6, lane = t & 63;

    if (bid < 256) {
        // ---- 32x32 tile of Wqk = Wq @ Wk^T (TRANS_B pattern, K=512) ----
        constexpr int LDK = 40;
        __shared__ __align__(16) unsigned short Ah[32 * LDK];
        __shared__ __align__(16) unsigned short Al[32 * LDK];
        __shared__ __align__(16) unsigned short Bh[32 * LDK];
        __shared__ __align__(16) unsigned short Bl[32 * LDK];
        const int m0 = (bid >> 4) * 32, n0 = (bid & 15) * 32;
        const int wm = (wave & 1) * 16, wn = (wave >> 1) * 16;
        float4v acc = (float4v){0.f, 0.f, 0.f, 0.f};
        const int arow = wm + (lane & 15);
        const int brow = wn + (lane & 15);
        const int kq8 = (lane >> 4) * 8;
        const int srow = t >> 3, skq = (t & 7) * 4;

        float4 va = *(const float4*)(Wq + (size_t)(m0 + srow) * 512 + skq);
        float4 vb = *(const float4*)(Wk + (size_t)(n0 + srow) * 512 + skq);
        for (int k0 = 0; k0 < 512; k0 += 32) {
            {
                unsigned short h0 = f2bf(va.x), h1 = f2bf(va.y), h2 = f2bf(va.z), h3 = f2bf(va.w);
                short4v hv = {(short)h0, (short)h1, (short)h2, (short)h3};
                short4v lv = {(short)f2bf(va.x - bf2f(h0)), (short)f2bf(va.y - bf2f(h1)),
                              (short)f2bf(va.z - bf2f(h2)), (short)f2bf(va.w - bf2f(h3))};
                *(short4v*)&Ah[srow * LDK + skq] = hv;
                *(short4v*)&Al[srow * LDK + skq] = lv;
            }
            {
                unsigned short h0 = f2bf(vb.x), h1 = f2bf(vb.y), h2 = f2bf(vb.z), h3 = f2bf(vb.w);
                short4v hv = {(short)h0, (short)h1, (short)h2, (short)h3};
                short4v lv = {(short)f2bf(vb.x - bf2f(h0)), (short)f2bf(vb.y - bf2f(h1)),
                              (short)f2bf(vb.z - bf2f(h2)), (short)f2bf(vb.w - bf2f(h3))};
                *(short4v*)&Bh[srow * LDK + skq] = hv;
                *(short4v*)&Bl[srow * LDK + skq] = lv;
            }
            float4 va2, vb2;
            if (k0 + 32 < 512) {
                va2 = *(const float4*)(Wq + (size_t)(m0 + srow) * 512 + k0 + 32 + skq);
                vb2 = *(const float4*)(Wk + (size_t)(n0 + srow) * 512 + k0 + 32 + skq);
            } else { va2 = va; vb2 = vb; }
            __syncthreads();
            short8 ah = *(const short8*)&Ah[arow * LDK + kq8];
            short8 al = *(const short8*)&Al[arow * LDK + kq8];
            short8 bh = *(const short8*)&Bh[brow * LDK + kq8];
            short8 bl = *(const short8*)&Bl[brow * LDK + kq8];
            acc = __builtin_amdgcn_mfma_f32_16x16x32_bf16(ah, bh, acc, 0, 0, 0);
            acc = __builtin_amdgcn_mfma_f32_16x16x32_bf16(ah, bl, acc, 0, 0, 0);
            acc = __builtin_amdgcn_mfma_f32_16x16x32_bf16(al, bh, acc, 0, 0, 0);
            __syncthreads();
            va = va2; vb = vb2;
        }
        const int coln = lane & 15, rbase = (lane >> 4) * 4;
        const int n = n0 + wn + coln;
#pragma unroll
        for (int r = 0; r < 4; ++r)
            Wqk[(size_t)(m0 + wm + rbase + r) * 512 + n] = acc[r];
    } else if (bid < 264) {
        // wv[m] = Wq[m,:] . bk   (8 blocks x 64 rows)
        const int gb = bid - 256;
        float4 w0 = *(const float4*)(bk + 4 * lane);
        float4 w1 = *(const float4*)(bk + 256 + 4 * lane);
        for (int i = 0; i < 16; ++i) {
            int m = gb * 64 + wave * 16 + i;
            float d = dot512(Wq + (size_t)m * 512, w0, w1, lane);
            if (lane == 0) wv[m] = d;
        }
    } else if (bid < 272) {
        // bqk[n] = bq . Wk[n,:] ; c0 = bq . bk  (8 blocks x 64 rows)
        const int gb = bid - 264;
        float4 w0 = *(const float4*)(bq + 4 * lane);
        float4 w1 = *(const float4*)(bq + 256 + 4 * lane);
        for (int i = 0; i < 16; ++i) {
            int n = gb * 64 + wave * 16 + i;
            float d = dot512(Wk + (size_t)n * 512, w0, w1, lane);
            if (lane == 0) bqk[n] = d;
        }
        if (gb == 0 && wave == 0) {
            float d = dot512(bk, w0, w1, lane);  // bq·bk
            if (lane == 0) c0[0] = d;
        }
    } else {
        // bvo[n] = sum_k bv[k]*Wo[k,n] + bo[n]  (8 blocks x 64 cols)
        const int gb = bid - 272;
        if (t < 64) {
            int n = gb * 64 + t;
            float a = 0.f;
#pragma unroll 4
            for (int k = 0; k < 512; ++k)
                a = fmaf(bv[k], Wo[(size_t)k * 512 + n], a);
            bvo[n] = a + bo[n];
        }
    }
}

// ---------------------------------------------------------------------------
// Row LayerNorm + s0 epilogue: y = LN(x)*g+b ; s0[row] = y·wv + c0
// (R2-proven, verbatim)
// ---------------------------------------------------------------------------
__global__ __launch_bounds__(64) void ln_s0_k(const float* __restrict__ x,
                                              const float* __restrict__ g,
                                              const float* __restrict__ be,
                                              const float* __restrict__ wv,
                                              const float* __restrict__ c0,
                                              float* __restrict__ y,
                                              float* __restrict__ s0) {
    const int row = blockIdx.x;
    const int lane = threadIdx.x;
    const float* xr = x + (size_t)row * ND;
    float4 x0 = *(const float4*)(xr + 4 * lane);
    float4 x1 = *(const float4*)(xr + 256 + 4 * lane);
    float s1 = x0.x + x0.y + x0.z + x0.w + x1.x + x1.y + x1.z + x1.w;
    float s2 = x0.x * x0.x + x0.y * x0.y + x0.z * x0.z + x0.w * x0.w +
               x1.x * x1.x + x1.y * x1.y + x1.z * x1.z + x1.w * x1.w;
    for (int off = 32; off; off >>= 1) {
        s1 += __shfl_xor(s1, off, 64);
        s2 += __shfl_xor(s2, off, 64);
    }
    float mean = s1 * (1.f / 512.f);
    float rstd = rsqrtf(s2 * (1.f / 512.f) - mean * mean + LN_EPS);
    float4 g0 = *(const float4*)(g + 4 * lane);
    float4 g1 = *(const float4*)(g + 256 + 4 * lane);
    float4 b0 = *(const float4*)(be + 4 * lane);
    float4 b1 = *(const float4*)(be + 256 + 4 * lane);
    float4 y0, y1;
    y0.x = (x0.x - mean) * rstd * g0.x + b0.x;
    y0.y = (x0.y - mean) * rstd * g0.y + b0.y;
    y0.z = (x0.z - mean) * rstd * g0.z + b0.z;
    y0.w = (x0.w - mean) * rstd * g0.w + b0.w;
    y1.x = (x1.x - mean) * rstd * g1.x + b1.x;
    y1.y = (x1.y - mean) * rstd * g1.y + b1.y;
    y1.z = (x1.z - mean) * rstd * g1.z + b1.z;
    y1.w = (x1.w - mean) * rstd * g1.w + b1.w;
    float* yr = y + (size_t)row * ND;
    *(float4*)(yr + 4 * lane) = y0;
    *(float4*)(yr + 256 + 4 * lane) = y1;
    // s0 = y . wv + c0
    float4 w0 = *(const float4*)(wv + 4 * lane);
    float4 w1 = *(const float4*)(wv + 256 + 4 * lane);
    float d = y0.x * w0.x + y0.y * w0.y + y0.z * w0.z + y0.w * w0.w +
              y1.x * w1.x + y1.y * w1.y + y1.z * w1.z + y1.w * w1.w;
    for (int off = 32; off; off >>= 1) d += __shfl_xor(d, off, 64);
    if (lane == 0) s0[row] = d + c0[0];
}

// ---------------------------------------------------------------------------
// Split-bf16 MFMA GEMM, 32x32 tiles (non-trans B): C = A@B (+bias)
// EPI=2: gate epilogue — z = acc + e_add[m,n]; a=sigmoid(z);
//        C = a*e_ctx + (1-a)*e_sent
// (R2-proven, verbatim)
// ---------------------------------------------------------------------------
template <int EPI>
__global__ __launch_bounds__(256) void gemm32_k(
    const float* __restrict__ A, const float* __restrict__ B,
    const float* __restrict__ bias, float* __restrict__ C, int N, int K,
    const float* __restrict__ e_ctx, const float* __restrict__ e_sent,
    const float* __restrict__ e_add) {
    constexpr int LDK = 40;
    __shared__ __align__(16) unsigned short Ah[32 * LDK];
    __shared__ __align__(16) unsigned short Al[32 * LDK];
    __shared__ __align__(16) unsigned short Bh[32 * LDK];
    __shared__ __align__(16) unsigned short Bl[32 * LDK];
    const int t = threadIdx.x;
    const int wave = t >> 6, lane = t & 63;
    const int m0 = blockIdx.y * 32, n0 = blockIdx.x * 32;
    const int wm = (wave & 1) * 16, wn = (wave >> 1) * 16;

    float4v acc = (float4v){0.f, 0.f, 0.f, 0.f};
    const int arow = wm + (lane & 15);
    const int brow = wn + (lane & 15);
    const int kq8 = (lane >> 4) * 8;
    const int srow = t >> 3, skq = (t & 7) * 4;

    float4 va = *(const float4*)(A + (size_t)(m0 + srow) * K + skq);
    float4 vb = *(const float4*)(B + (size_t)srow * N + n0 + skq);

    for (int k0 = 0; k0 < K; k0 += 32) {
        {
            unsigned short h0 = f2bf(va.x), h1 = f2bf(va.y), h2 = f2bf(va.z), h3 = f2bf(va.w);
            short4v hv = {(short)h0, (short)h1, (short)h2, (short)h3};
            short4v lv = {(short)f2bf(va.x - bf2f(h0)), (short)f2bf(va.y - bf2f(h1)),
                          (short)f2bf(va.z - bf2f(h2)), (short)f2bf(va.w - bf2f(h3))};
            *(short4v*)&Ah[srow * LDK + skq] = hv;
            *(short4v*)&Al[srow * LDK + skq] = lv;
        }
        {
            // srow = k-row, skq = n-quad; scatter-transpose into [n][k]
            float vv[4] = {vb.x, vb.y, vb.z, vb.w};
#pragma unroll
            for (int j = 0; j < 4; ++j) {
                unsigned short hh = f2bf(vv[j]);
                Bh[(skq + j) * LDK + srow] = hh;
                Bl[(skq + j) * LDK + srow] = f2bf(vv[j] - bf2f(hh));
            }
        }
        float4 va2, vb2;
        if (k0 + 32 < K) {
            va2 = *(const float4*)(A + (size_t)(m0 + srow) * K + k0 + 32 + skq);
            vb2 = *(const float4*)(B + (size_t)(k0 + 32 + srow) * N + n0 + skq);
        } else { va2 = va; vb2 = vb; }
        __syncthreads();
        short8 ah = *(const short8*)&Ah[arow * LDK + kq8];
        short8 al = *(const short8*)&Al[arow * LDK + kq8];
        short8 bh = *(const short8*)&Bh[brow * LDK + kq8];
        short8 bl = *(const short8*)&Bl[brow * LDK + kq8];
        acc = __builtin_amdgcn_mfma_f32_16x16x32_bf16(ah, bh, acc, 0, 0, 0);
        acc = __builtin_amdgcn_mfma_f32_16x16x32_bf16(ah, bl, acc, 0, 0, 0);
        acc = __builtin_amdgcn_mfma_f32_16x16x32_bf16(al, bh, acc, 0, 0, 0);
        __syncthreads();
        va = va2; vb = vb2;
    }

    const int coln = lane & 15, rbase = (lane >> 4) * 4;
    const int n = n0 + wn + coln;
    const float bvv = bias ? bias[n] : 0.f;
#pragma unroll
    for (int r = 0; r < 4; ++r) {
        int m = m0 + wm + rbase + r;
        float val = acc[r] + bvv;
        if (EPI == 2) {
            float z = val + e_add[(size_t)m * N + n];
            float a = 1.f / (1.f + __expf(-z));
            float cx = e_ctx[(size_t)m * N + n];
            float sv = e_sent[(size_t)m * N + n];
            val = a * cx + (1.f - a) * sv;
        }
        C[(size_t)m * N + n] = val;
    }
}

// ---------------------------------------------------------------------------
// Flash pass (R1/R2-proven, verbatim): per (b,s) row, score and weighted
// accumulation without materializing LN. Runs ALONE on the chip.
// ---------------------------------------------------------------------------
__global__ __launch_bounds__(512) void flash_k(const float* __restrict__ ps,
                                               const float* __restrict__ g,
                                               const float* __restrict__ be,
                                               const float* __restrict__ qp,
                                               const float* __restrict__ s0v,
                                               float* __restrict__ ctx_pre,
                                               float* __restrict__ attn) {
    const int b = blockIdx.x;
    const int t = threadIdx.x;
    const int wave = t >> 6, lane = t & 63;
    __shared__ float zbuf[NS];
    __shared__ float ubuf[8][ND];
    __shared__ float lw[8], tw[8];

    const float* qb = qp + (size_t)b * ND;
    float4 q0 = *(const float4*)(qb + 4 * lane);
    float4 q1 = *(const float4*)(qb + 256 + 4 * lane);
    float4 g0 = *(const float4*)(g + 4 * lane);
    float4 g1 = *(const float4*)(g + 256 + 4 * lane);
    float4 b0 = *(const float4*)(be + 4 * lane);
    float4 b1 = *(const float4*)(be + 256 + 4 * lane);

    float4 qg0, qg1;
    qg0.x = g0.x * q0.x; qg0.y = g0.y * q0.y; qg0.z = g0.z * q0.z; qg0.w = g0.w * q0.w;
    qg1.x = g1.x * q1.x; qg1.y = g1.y * q1.y; qg1.z = g1.z * q1.z; qg1.w = g1.w * q1.w;
    float c1 = qg0.x + qg0.y + qg0.z + qg0.w + qg1.x + qg1.y + qg1.z + qg1.w;
    float c2 = b0.x * q0.x + b0.y * q0.y + b0.z * q0.z + b0.w * q0.w +
               b1.x * q1.x + b1.y * q1.y + b1.z * q1.z + b1.w * q1.w;
    for (int off = 32; off; off >>= 1) {
        c1 += __shfl_xor(c1, off, 64);
        c2 += __shfl_xor(c2, off, 64);
    }
    const float K2 = INV_SCALE * (c2 + s0v[b]);
    const float C1 = c1;

    float l = 0.f, t1 = 0.f;
    float4 u0 = {0.f, 0.f, 0.f, 0.f}, u1 = {0.f, 0.f, 0.f, 0.f};

    const float* base = ps + ((size_t)b * NS + wave * 64) * ND + 4 * lane;
    float4 xa0 = *(const float4*)(base);
    float4 xa1 = *(const float4*)(base + 256);
    float4 xb0 = *(const float4*)(base + ND);
    float4 xb1 = *(const float4*)(base + ND + 256);

    for (int r = 0; r < 64; r += 2) {
        float4 ya0, ya1, yb0, yb1;
        if (r < 62) {
            const float* nb = base + (size_t)(r + 2) * ND;
            ya0 = *(const float4*)(nb);
            ya1 = *(const float4*)(nb + 256);
            yb0 = *(const float4*)(nb + ND);
            yb1 = *(const float4*)(nb + ND + 256);
        } else {
            ya0 = xa0; ya1 = xa1; yb0 = xb0; yb1 = xb1;
        }
        float sa1 = xa0.x + xa0.y + xa0.z + xa0.w + xa1.x + xa1.y + xa1.z + xa1.w;
        float sb1 = xb0.x + xb0.y + xb0.z + xb0.w + xb1.x + xb1.y + xb1.z + xb1.w;
        float sa2 = xa0.x * xa0.x + xa0.y * xa0.y + xa0.z * xa0.z + xa0.w * xa0.w +
                    xa1.x * xa1.x + xa1.y * xa1.y + xa1.z * xa1.z + xa1.w * xa1.w;
        float sb2 = xb0.x * xb0.x + xb0.y * xb0.y + xb0.z * xb0.z + xb0.w * xb0.w +
                    xb1.x * xb1.x + xb1.y * xb1.y + xb1.z * xb1.z + xb1.w * xb1.w;
        float sa3 = xa0.x * qg0.x + xa0.y * qg0.y + xa0.z * qg0.z + xa0.w * qg0.w +
                    xa1.x * qg1.x + xa1.y * qg1.y + xa1.z * qg1.z + xa1.w * qg1.w;
        float sb3 = xb0.x * qg0.x + xb0.y * qg0.y + xb0.z * qg0.z + xb0.w * qg0.w +
                    xb1.x * qg1.x + xb1.y * qg1.y + xb1.z * qg1.z + xb1.w * qg1.w;
        for (int off = 32; off; off >>= 1) {
            sa1 += __shfl_xor(sa1, off, 64);
            sb1 += __shfl_xor(sb1, off, 64);
            sa2 += __shfl_xor(sa2, off, 64);
            sb2 += __shfl_xor(sb2, off, 64);
            sa3 += __shfl_xor(sa3, off, 64);
            sb3 += __shfl_xor(sb3, off, 64);
        }
        float meana = sa1 * (1.f / 512.f), meanb = sb1 * (1.f / 512.f);
        float rstda = rsqrtf(sa2 * (1.f / 512.f) - meana * meana + LN_EPS);
        float rstdb = rsqrtf(sb2 * (1.f / 512.f) - meanb * meanb + LN_EPS);
        float za = INV_SCALE * rstda * (sa3 - meana * C1) + K2;
        float zb = INV_SCALE * rstdb * (sb3 - meanb * C1) + K2;
        float pa = __expf(za), pb = __expf(zb);
        l += pa + pb;
        float pra = pa * rstda, prb = pb * rstdb;
        t1 += pra * meana + prb * meanb;
        u0.x += pra * xa0.x + prb * xb0.x;
        u0.y += pra * xa0.y + prb * xb0.y;
        u0.z += pra * xa0.z + prb * xb0.z;
        u0.w += pra * xa0.w + prb * xb0.w;
        u1.x += pra * xa1.x + prb * xb1.x;
        u1.y += pra * xa1.y + prb * xb1.y;
        u1.z += pra * xa1.z + prb * xb1.z;
        u1.w += pra * xa1.w + prb * xb1.w;
        if (lane == 0) {
            zbuf[wave * 64 + r] = za;
            zbuf[wave * 64 + r + 1] = zb;
        }
        xa0 = ya0; xa1 = ya1; xb0 = yb0; xb1 = yb1;
    }

    *(float4*)&ubuf[wave][4 * lane] = u0;
    *(float4*)&ubuf[wave][256 + 4 * lane] = u1;
    if (lane == 0) { lw[wave] = l; tw[wave] = t1; }
    __syncthreads();

    float U = 0.f;
#pragma unroll
    for (int w = 0; w < 8; ++w) U += ubuf[w][t];
    float L = 0.f, T = 0.f;
#pragma unroll
    for (int w = 0; w < 8; ++w) { L += lw[w]; T += tw[w]; }
    float invL = 1.f / L;
    ctx_pre[(size_t)b * ND + t] = g[t] * (U - T) * invL + be[t];
    attn[(size_t)b * NS + t] = __expf(zbuf[t]) * invL;
}

// ---------------------------------------------------------------------------
extern "C" void kernel_launch(void* const* d_in, const int* in_sizes, int n_in,
                              void* d_out, int out_size, void* d_ws, size_t ws_size,
                              hipStream_t stream) {
    const float* sent = (const float*)d_in[0];
    const float* ps   = (const float*)d_in[1];
    const float* Wq = (const float*)d_in[2];
    const float* bq = (const float*)d_in[3];
    const float* Wk = (const float*)d_in[4];
    const float* bk = (const float*)d_in[5];
    const float* Wv = (const float*)d_in[6];
    const float* bv = (const float*)d_in[7];
    const float* Wo = (const float*)d_in[8];
    const float* bo = (const float*)d_in[9];
    const float* Wg = (const float*)d_in[10];
    const float* bg = (const float*)d_in[11];
    const float* g_q = (const float*)d_in[12];
    const float* beta_q = (const float*)d_in[13];
    const float* g_kv = (const float*)d_in[14];
    const float* beta_kv = (const float*)d_in[15];

    float* out = (float*)d_out;            // fused [B,D]
    float* attn = out + NB * ND;           // attn  [B,S]

    float* ws = (float*)d_ws;
    float* Wqk     = ws;                   // 262144
    float* Wvo     = ws + 262144;          // 262144
    float* sentg   = ws + 524288;          // 262144
    float* Qln     = ws + 786432;          // 262144
    float* qprime  = ws + 1048576;         // 262144
    float* ctx_pre = ws + 1310720;         // 262144
    float* ctx2    = ws + 1572864;         // 262144
    float* wv      = ws + 1835008;         // 512
    float* bqk     = ws + 1835520;         // 512
    float* bvo     = ws + 1836032;         // 512
    float* s0      = ws + 1836544;         // 512
    float* c0      = ws + 1837056;         // 1

    dim3 g32(16, 16);

    // L1: weight-only prep (Wqk = Wq@Wk^T, wv, bqk, bvo, c0)
    prep_k<<<280, 256, 0, stream>>>(Wq, Wk, bq, bk, bv, Wo, bo,
                                    Wqk, wv, bqk, bvo, c0);
    // L2: Wvo = Wv @ Wo (weight-only)
    gemm32_k<0><<<g32, 256, 0, stream>>>(Wv, Wo, nullptr, Wvo, 512, 512,
                                         nullptr, nullptr, nullptr);
    // L3: sentg = sent @ Wg_top + bg (input-only)
    gemm32_k<0><<<g32, 256, 0, stream>>>(sent, Wg, bg, sentg, 512, 512,
                                         nullptr, nullptr, nullptr);
    // L4: Qln = LN(sent); s0 = Qln·wv + c0
    ln_s0_k<<<NB, 64, 0, stream>>>(sent, g_q, beta_q, wv, c0, Qln, s0);
    // L5: qprime = Qln @ Wqk + bqk
    gemm32_k<0><<<g32, 256, 0, stream>>>(Qln, Wqk, bqk, qprime, 512, 512,
                                         nullptr, nullptr, nullptr);
    // L6: flash over price_sequence (alone on the chip)
    flash_k<<<NB, 512, 0, stream>>>(ps, g_kv, beta_kv, qprime, s0, ctx_pre, attn);
    // L7: ctx2 = ctx_pre @ Wvo + bvo
    gemm32_k<0><<<g32, 256, 0, stream>>>(ctx_pre, Wvo, bvo, ctx2, 512, 512,
                                         nullptr, nullptr, nullptr);
    // L8: out = sigmoid(ctx2@Wg_bot + sentg) gate, fused with ctx2/sent
    gemm32_k<2><<<g32, 256, 0, stream>>>(ctx2, Wg + 512 * 512, nullptr, out,
                                         512, 512, ctx2, sent, sentg);
}

// Round 6
// 771.697 us; speedup vs baseline: 1.0829x; 1.0829x over previous
//
#include <hip/hip_runtime.h>

// Problem constants (fixed by setup_inputs): B=512, S=512, D=512
#define NB 512
#define NS 512
#define ND 512
#define INV_SCALE 0.125f   // 1/sqrt(D/8=64)
#define LN_EPS 1e-5f

typedef __attribute__((ext_vector_type(8))) short short8;
typedef __attribute__((ext_vector_type(4))) short short4v;
typedef __attribute__((ext_vector_type(4))) float float4v;

static __device__ __forceinline__ unsigned short f2bf(float x) {
    unsigned int u = __float_as_uint(x);
    unsigned int r = (u + 0x7fffu + ((u >> 16) & 1u)) >> 16;
    return (unsigned short)r;
}
static __device__ __forceinline__ float bf2f(unsigned short h) {
    return __uint_as_float(((unsigned int)h) << 16);
}

// split-bf16 convert a float4 and store hi/lo at H/L[idx..idx+3] (vectorized)
static __device__ __forceinline__ void stage_vec(unsigned short* __restrict__ H,
                                                 unsigned short* __restrict__ L,
                                                 int idx, float4 v) {
    unsigned short h0 = f2bf(v.x), h1 = f2bf(v.y), h2 = f2bf(v.z), h3 = f2bf(v.w);
    short4v hv = {(short)h0, (short)h1, (short)h2, (short)h3};
    short4v lv = {(short)f2bf(v.x - bf2f(h0)), (short)f2bf(v.y - bf2f(h1)),
                  (short)f2bf(v.z - bf2f(h2)), (short)f2bf(v.w - bf2f(h3))};
    *(short4v*)&H[idx] = hv;
    *(short4v*)&L[idx] = lv;
}

// ---------------------------------------------------------------------------
// Row LayerNorm: one wave per 512-elem row. y = (x-mean)*rstd*g + b
// (R1-proven, verbatim)
// ---------------------------------------------------------------------------
__global__ __launch_bounds__(64) void ln_rows_k(const float* __restrict__ x,
                                                const float* __restrict__ g,
                                                const float* __restrict__ be,
                                                float* __restrict__ y) {
    const int row = blockIdx.x;
    const int lane = threadIdx.x;
    const float* xr = x + (size_t)row * ND;
    float4 x0 = *(const float4*)(xr + 4 * lane);
    float4 x1 = *(const float4*)(xr + 256 + 4 * lane);
    float s1 = x0.x + x0.y + x0.z + x0.w + x1.x + x1.y + x1.z + x1.w;
    float s2 = x0.x * x0.x + x0.y * x0.y + x0.z * x0.z + x0.w * x0.w +
               x1.x * x1.x + x1.y * x1.y + x1.z * x1.z + x1.w * x1.w;
    for (int off = 32; off; off >>= 1) {
        s1 += __shfl_xor(s1, off, 64);
        s2 += __shfl_xor(s2, off, 64);
    }
    float mean = s1 * (1.f / 512.f);
    float rstd = rsqrtf(s2 * (1.f / 512.f) - mean * mean + LN_EPS);
    float4 g0 = *(const float4*)(g + 4 * lane);
    float4 g1 = *(const float4*)(g + 256 + 4 * lane);
    float4 b0 = *(const float4*)(be + 4 * lane);
    float4 b1 = *(const float4*)(be + 256 + 4 * lane);
    float4 y0, y1;
    y0.x = (x0.x - mean) * rstd * g0.x + b0.x;
    y0.y = (x0.y - mean) * rstd * g0.y + b0.y;
    y0.z = (x0.z - mean) * rstd * g0.z + b0.z;
    y0.w = (x0.w - mean) * rstd * g0.w + b0.w;
    y1.x = (x1.x - mean) * rstd * g1.x + b1.x;
    y1.y = (x1.y - mean) * rstd * g1.y + b1.y;
    y1.z = (x1.z - mean) * rstd * g1.z + b1.z;
    y1.w = (x1.w - mean) * rstd * g1.w + b1.w;
    float* yr = y + (size_t)row * ND;
    *(float4*)(yr + 4 * lane) = y0;
    *(float4*)(yr + 256 + 4 * lane) = y1;
}

// ---------------------------------------------------------------------------
// s0[b] = dot(q[b,:], bk)  (one wave per row)  (R1-proven, verbatim)
// ---------------------------------------------------------------------------
__global__ __launch_bounds__(64) void rowdot_k(const float* __restrict__ q,
                                               const float* __restrict__ bk,
                                               float* __restrict__ s0) {
    const int row = blockIdx.x;
    const int lane = threadIdx.x;
    const float* qr = q + (size_t)row * ND;
    float4 a0 = *(const float4*)(qr + 4 * lane);
    float4 a1 = *(const float4*)(qr + 256 + 4 * lane);
    float4 c0 = *(const float4*)(bk + 4 * lane);
    float4 c1 = *(const float4*)(bk + 256 + 4 * lane);
    float d = a0.x * c0.x + a0.y * c0.y + a0.z * c0.z + a0.w * c0.w +
              a1.x * c1.x + a1.y * c1.y + a1.z * c1.z + a1.w * c1.w;
    for (int off = 32; off; off >>= 1) d += __shfl_xor(d, off, 64);
    if (lane == 0) s0[row] = d;
}

// ---------------------------------------------------------------------------
// Split-bf16 MFMA GEMM, 32x32 tiles, BK=64: C[M,N] = A@B (+bias).
// Same math/accumulation order as the R1 791.7µs kernel (sub0 triple then
// sub1 triple == two consecutive R1 K-steps -> bit-identical results);
// the only change is staging TWO 32-k sub-tiles per barrier pair, halving
// the barrier count (32 -> 16) that dominated the latency-bound GEMMs.
// A is split [A1 | A2] at column ksplit (for the K=1024 gate GEMM).
// EPI==1: sigmoid-gate epilogue.
// ---------------------------------------------------------------------------
template <bool TRANS_B, int EPI>
__global__ __launch_bounds__(256) void gemm32_k(
    const float* __restrict__ A1, const float* __restrict__ A2, int ksplit,
    const float* __restrict__ B, const float* __restrict__ bias,
    float* __restrict__ C, int M, int N, int K,
    const float* __restrict__ e_ctx, const float* __restrict__ e_sent) {
    constexpr int LDK = 40;
    __shared__ __align__(16) unsigned short Ah[2][32 * LDK];
    __shared__ __align__(16) unsigned short Al[2][32 * LDK];
    __shared__ __align__(16) unsigned short Bh[2][32 * LDK];
    __shared__ __align__(16) unsigned short Bl[2][32 * LDK];
    const int t = threadIdx.x;
    const int wave = t >> 6, lane = t & 63;
    const int m0 = blockIdx.y * 32, n0 = blockIdx.x * 32;
    const int wm = (wave & 1) * 16, wn = (wave >> 1) * 16;

    float4v acc = (float4v){0.f, 0.f, 0.f, 0.f};

    const int arow = wm + (lane & 15);
    const int brow = wn + (lane & 15);
    const int kq8 = (lane >> 4) * 8;
    // staging indices: 256 threads stage 32 rows x 32 k per sub-tile
    const int srow = t >> 3, skq = (t & 7) * 4;

    // A load for global k-quad kg (handles the A1|A2 split)
    #define LOAD_A(kg) \
        (((kg) < ksplit) \
             ? *(const float4*)(A1 + (size_t)(m0 + srow) * ksplit + (kg)) \
             : *(const float4*)(A2 + (size_t)(m0 + srow) * (K - ksplit) + ((kg) - ksplit)))
    // B load for sub-tile starting at global k-row k0s
    #define LOAD_B(k0s) \
        (TRANS_B ? *(const float4*)(B + (size_t)(n0 + srow) * K + (k0s) + skq) \
                 : *(const float4*)(B + (size_t)((k0s) + srow) * N + n0 + skq))

    // --- prefetch K-step 0 (two 32-k sub-tiles) ---
    float4 va0 = LOAD_A(skq);
    float4 va1 = LOAD_A(32 + skq);
    float4 vb0 = LOAD_B(0);
    float4 vb1 = LOAD_B(32);

    for (int k0 = 0; k0 < K; k0 += 64) {
        // stage both sub-tiles
        stage_vec(Ah[0], Al[0], srow * LDK + skq, va0);
        stage_vec(Ah[1], Al[1], srow * LDK + skq, va1);
        if (TRANS_B) {
            stage_vec(Bh[0], Bl[0], srow * LDK + skq, vb0);
            stage_vec(Bh[1], Bl[1], srow * LDK + skq, vb1);
        } else {
            // srow = k-row, skq = n-quad; scatter-transpose into [n][k]
            float v0[4] = {vb0.x, vb0.y, vb0.z, vb0.w};
            float v1[4] = {vb1.x, vb1.y, vb1.z, vb1.w};
#pragma unroll
            for (int j = 0; j < 4; ++j) {
                unsigned short h0 = f2bf(v0[j]);
                Bh[0][(skq + j) * LDK + srow] = h0;
                Bl[0][(skq + j) * LDK + srow] = f2bf(v0[j] - bf2f(h0));
                unsigned short h1 = f2bf(v1[j]);
                Bh[1][(skq + j) * LDK + srow] = h1;
                Bl[1][(skq + j) * LDK + srow] = f2bf(v1[j] - bf2f(h1));
            }
        }
        // issue next K-step's global loads before the barrier; the vmcnt wait
        // lands at the register copy below, overlapped with the MFMA phase
        float4 na0 = va0, na1 = va1, nb0 = vb0, nb1 = vb1;
        if (k0 + 64 < K) {
            na0 = LOAD_A(k0 + 64 + skq);
            na1 = LOAD_A(k0 + 96 + skq);
            nb0 = LOAD_B(k0 + 64);
            nb1 = LOAD_B(k0 + 96);
        }
        __syncthreads();
#pragma unroll
        for (int s = 0; s < 2; ++s) {
            short8 ah = *(const short8*)&Ah[s][arow * LDK + kq8];
            short8 al = *(const short8*)&Al[s][arow * LDK + kq8];
            short8 bh = *(const short8*)&Bh[s][brow * LDK + kq8];
            short8 bl = *(const short8*)&Bl[s][brow * LDK + kq8];
            acc = __builtin_amdgcn_mfma_f32_16x16x32_bf16(ah, bh, acc, 0, 0, 0);
            acc = __builtin_amdgcn_mfma_f32_16x16x32_bf16(ah, bl, acc, 0, 0, 0);
            acc = __builtin_amdgcn_mfma_f32_16x16x32_bf16(al, bh, acc, 0, 0, 0);
        }
        __syncthreads();
        va0 = na0; va1 = na1; vb0 = nb0; vb1 = nb1;
    }
    #undef LOAD_A
    #undef LOAD_B

    const int coln = lane & 15, rbase = (lane >> 4) * 4;
    const int n = n0 + wn + coln;
    const float bv = bias ? bias[n] : 0.f;
#pragma unroll
    for (int r = 0; r < 4; ++r) {
        int m = m0 + wm + rbase + r;
        float val = acc[r] + bv;
        if (EPI == 1) {
            float a = 1.f / (1.f + __expf(-val));
            float cx = e_ctx[(size_t)m * N + n];
            float sv = e_sent[(size_t)m * N + n];
            val = a * cx + (1.f - a) * sv;
        }
        C[(size_t)m * N + n] = val;
    }
}

// ---------------------------------------------------------------------------
// Flash pass (R1-proven, verbatim): per (b,s) row, score and weighted
// accumulation without materializing LN. Runs alone on the chip.
// ---------------------------------------------------------------------------
__global__ __launch_bounds__(512) void flash_k(const float* __restrict__ ps,
                                               const float* __restrict__ g,
                                               const float* __restrict__ be,
                                               const float* __restrict__ qp,
                                               const float* __restrict__ s0v,
                                               float* __restrict__ ctx_pre,
                                               float* __restrict__ attn) {
    const int b = blockIdx.x;
    const int t = threadIdx.x;
    const int wave = t >> 6, lane = t & 63;
    __shared__ float zbuf[NS];
    __shared__ float ubuf[8][ND];
    __shared__ float lw[8], tw[8];

    const float* qb = qp + (size_t)b * ND;
    float4 q0 = *(const float4*)(qb + 4 * lane);
    float4 q1 = *(const float4*)(qb + 256 + 4 * lane);
    float4 g0 = *(const float4*)(g + 4 * lane);
    float4 g1 = *(const float4*)(g + 256 + 4 * lane);
    float4 b0 = *(const float4*)(be + 4 * lane);
    float4 b1 = *(const float4*)(be + 256 + 4 * lane);

    float4 qg0, qg1;
    qg0.x = g0.x * q0.x; qg0.y = g0.y * q0.y; qg0.z = g0.z * q0.z; qg0.w = g0.w * q0.w;
    qg1.x = g1.x * q1.x; qg1.y = g1.y * q1.y; qg1.z = g1.z * q1.z; qg1.w = g1.w * q1.w;
    float c1 = qg0.x + qg0.y + qg0.z + qg0.w + qg1.x + qg1.y + qg1.z + qg1.w;
    float c2 = b0.x * q0.x + b0.y * q0.y + b0.z * q0.z + b0.w * q0.w +
               b1.x * q1.x + b1.y * q1.y + b1.z * q1.z + b1.w * q1.w;
    for (int off = 32; off; off >>= 1) {
        c1 += __shfl_xor(c1, off, 64);
        c2 += __shfl_xor(c2, off, 64);
    }
    const float K2 = INV_SCALE * (c2 + s0v[b]);
    const float C1 = c1;

    float l = 0.f, t1 = 0.f;
    float4 u0 = {0.f, 0.f, 0.f, 0.f}, u1 = {0.f, 0.f, 0.f, 0.f};

    const float* base = ps + ((size_t)b * NS + wave * 64) * ND + 4 * lane;
    float4 xa0 = *(const float4*)(base);
    float4 xa1 = *(const float4*)(base + 256);
    float4 xb0 = *(const float4*)(base + ND);
    float4 xb1 = *(const float4*)(base + ND + 256);

    for (int r = 0; r < 64; r += 2) {
        float4 ya0, ya1, yb0, yb1;
        if (r < 62) {
            const float* nb = base + (size_t)(r + 2) * ND;
            ya0 = *(const float4*)(nb);
            ya1 = *(const float4*)(nb + 256);
            yb0 = *(const float4*)(nb + ND);
            yb1 = *(const float4*)(nb + ND + 256);
        } else {
            ya0 = xa0; ya1 = xa1; yb0 = xb0; yb1 = xb1;
        }
        float sa1 = xa0.x + xa0.y + xa0.z + xa0.w + xa1.x + xa1.y + xa1.z + xa1.w;
        float sb1 = xb0.x + xb0.y + xb0.z + xb0.w + xb1.x + xb1.y + xb1.z + xb1.w;
        float sa2 = xa0.x * xa0.x + xa0.y * xa0.y + xa0.z * xa0.z + xa0.w * xa0.w +
                    xa1.x * xa1.x + xa1.y * xa1.y + xa1.z * xa1.z + xa1.w * xa1.w;
        float sb2 = xb0.x * xb0.x + xb0.y * xb0.y + xb0.z * xb0.z + xb0.w * xb0.w +
                    xb1.x * xb1.x + xb1.y * xb1.y + xb1.z * xb1.z + xb1.w * xb1.w;
        float sa3 = xa0.x * qg0.x + xa0.y * qg0.y + xa0.z * qg0.z + xa0.w * qg0.w +
                    xa1.x * qg1.x + xa1.y * qg1.y + xa1.z * qg1.z + xa1.w * qg1.w;
        float sb3 = xb0.x * qg0.x + xb0.y * qg0.y + xb0.z * qg0.z + xb0.w * qg0.w +
                    xb1.x * qg1.x + xb1.y * qg1.y + xb1.z * qg1.z + xb1.w * qg1.w;
        for (int off = 32; off; off >>= 1) {
            sa1 += __shfl_xor(sa1, off, 64);
            sb1 += __shfl_xor(sb1, off, 64);
            sa2 += __shfl_xor(sa2, off, 64);
            sb2 += __shfl_xor(sb2, off, 64);
            sa3 += __shfl_xor(sa3, off, 64);
            sb3 += __shfl_xor(sb3, off, 64);
        }
        float meana = sa1 * (1.f / 512.f), meanb = sb1 * (1.f / 512.f);
        float rstda = rsqrtf(sa2 * (1.f / 512.f) - meana * meana + LN_EPS);
        float rstdb = rsqrtf(sb2 * (1.f / 512.f) - meanb * meanb + LN_EPS);
        float za = INV_SCALE * rstda * (sa3 - meana * C1) + K2;
        float zb = INV_SCALE * rstdb * (sb3 - meanb * C1) + K2;
        float pa = __expf(za), pb = __expf(zb);
        l += pa + pb;
        float pra = pa * rstda, prb = pb * rstdb;
        t1 += pra * meana + prb * meanb;
        u0.x += pra * xa0.x + prb * xb0.x;
        u0.y += pra * xa0.y + prb * xb0.y;
        u0.z += pra * xa0.z + prb * xb0.z;
        u0.w += pra * xa0.w + prb * xb0.w;
        u1.x += pra * xa1.x + prb * xb1.x;
        u1.y += pra * xa1.y + prb * xb1.y;
        u1.z += pra * xa1.z + prb * xb1.z;
        u1.w += pra * xa1.w + prb * xb1.w;
        if (lane == 0) {
            zbuf[wave * 64 + r] = za;
            zbuf[wave * 64 + r + 1] = zb;
        }
        xa0 = ya0; xa1 = ya1; xb0 = yb0; xb1 = yb1;
    }

    *(float4*)&ubuf[wave][4 * lane] = u0;
    *(float4*)&ubuf[wave][256 + 4 * lane] = u1;
    if (lane == 0) { lw[wave] = l; tw[wave] = t1; }
    __syncthreads();

    float U = 0.f;
#pragma unroll
    for (int w = 0; w < 8; ++w) U += ubuf[w][t];
    float L = 0.f, T = 0.f;
#pragma unroll
    for (int w = 0; w < 8; ++w) { L += lw[w]; T += tw[w]; }
    float invL = 1.f / L;
    ctx_pre[(size_t)b * ND + t] = g[t] * (U - T) * invL + be[t];
    attn[(size_t)b * NS + t] = __expf(zbuf[t]) * invL;
}

// ---------------------------------------------------------------------------
extern "C" void kernel_launch(void* const* d_in, const int* in_sizes, int n_in,
                              void* d_out, int out_size, void* d_ws, size_t ws_size,
                              hipStream_t stream) {
    const float* sent = (const float*)d_in[0];
    const float* ps   = (const float*)d_in[1];
    const float* Wq = (const float*)d_in[2];
    const float* bq = (const float*)d_in[3];
    const float* Wk = (const float*)d_in[4];
    const float* bk = (const float*)d_in[5];
    const float* Wv = (const float*)d_in[6];
    const float* bv = (const float*)d_in[7];
    const float* Wo = (const float*)d_in[8];
    const float* bo = (const float*)d_in[9];
    const float* Wg = (const float*)d_in[10];
    const float* bg = (const float*)d_in[11];
    const float* g_q = (const float*)d_in[12];
    const float* beta_q = (const float*)d_in[13];
    const float* g_kv = (const float*)d_in[14];
    const float* beta_kv = (const float*)d_in[15];

    float* out = (float*)d_out;            // fused [B,D]
    float* attn = out + NB * ND;           // attn  [B,S]

    float* ws = (float*)d_ws;
    float* Qln     = ws;                   // 262144
    float* q       = ws + 262144;          // 262144
    float* qprime  = ws + 524288;          // 262144
    float* s0      = ws + 786432;          // 512
    float* ctx_pre = ws + 786944;          // 262144
    float* ctx1    = ws + 1049088;         // 262144
    float* ctx2    = ws + 1311232;         // 262144

    dim3 g32(16, 16);

    // Q-chain
    ln_rows_k<<<NB, 64, 0, stream>>>(sent, g_q, beta_q, Qln);
    gemm32_k<false, 0><<<g32, 256, 0, stream>>>(
        Qln, nullptr, 512, Wq, bq, q, 512, 512, 512, nullptr, nullptr);
    rowdot_k<<<NB, 64, 0, stream>>>(q, bk, s0);
    gemm32_k<true, 0><<<g32, 256, 0, stream>>>(
        q, nullptr, 512, Wk, nullptr, qprime, 512, 512, 512, nullptr, nullptr);

    // Main streaming pass over price_sequence
    flash_k<<<NB, 512, 0, stream>>>(ps, g_kv, beta_kv, qprime, s0, ctx_pre, attn);

    // ctx chain
    gemm32_k<false, 0><<<g32, 256, 0, stream>>>(
        ctx_pre, nullptr, 512, Wv, bv, ctx1, 512, 512, 512, nullptr, nullptr);
    gemm32_k<false, 0><<<g32, 256, 0, stream>>>(
        ctx1, nullptr, 512, Wo, bo, ctx2, 512, 512, 512, nullptr, nullptr);

    // gate: [sent | ctx2] @ Wg + bg -> sigmoid -> fuse, straight to d_out
    gemm32_k<false, 1><<<g32, 256, 0, stream>>>(
        sent, ctx2, 512, Wg, bg, out, 512, 512, 1024, ctx2, sent);
}